// Round 1
// baseline (9.854 us; speedup 1.0000x reference)
//
#include <hip/hip_runtime.h>

// Z1_Layer_start: closed-form sparse fill of (AA[85,70,70], -b[85], A0[70,70]).
// Only v1, t, H1, c are used; rho1, mu1 are dead inputs.

#define MDIM 70
#define AA_ELEMS (85 * MDIM * MDIM)   // 416500
#define B_OFF    AA_ELEMS             // 85 elements
#define A0_OFF   (AA_ELEMS + 85)      // 4900 elements
#define TOT      (AA_ELEMS + 85 + MDIM * MDIM)  // 421485

__global__ __launch_bounds__(256) void z1_fill_kernel(
    const float* __restrict__ v1,   // 4
    const float* __restrict__ t,    // 4
    const float* __restrict__ H1,   // 8x8 row-major
    const float* __restrict__ c,    // 1
    float* __restrict__ out)
{
    int idx = blockIdx.x * blockDim.x + threadIdx.x;
    if (idx >= TOT) return;

    if (idx < AA_ELEMS) {
        // ---- AA[k, m, n] = -(concat(Asvec, Bsvec, A2)[k, m, n]) ----
        int k = idx / (MDIM * MDIM);
        int r = idx - k * (MDIM * MDIM);
        int m = r / MDIM;
        int n = r - m * MDIM;

        float val;
        if (k < 72) {
            const bool isB = (k >= 36);
            int kk = isB ? (k - 36) : k;
            // triu_indices(8) pair (i,j), row-major upper triangle
            int i = 0;
            while (kk >= 8 - i) { kk -= 8 - i; ++i; }
            int j = i + kk;

            // h columns of H = 0.2*H1: cols {0,2,5,7}
            float hi0 = 0.2f * H1[i * 8 + 0];
            float hi1 = 0.2f * H1[i * 8 + 2];
            float hi2 = 0.2f * H1[i * 8 + 5];
            float hi3 = 0.2f * H1[i * 8 + 7];
            float hj0 = 0.2f * H1[j * 8 + 0];
            float hj1 = 0.2f * H1[j * 8 + 2];
            float hj2 = 0.2f * H1[j * 8 + 5];
            float hj3 = 0.2f * H1[j * 8 + 7];

            float hiv[4] = {hi0, hi1, hi2, hi3};
            float hjv[4] = {hj0, hj1, hj2, hj3};

            float aij = 0.0f, aji = 0.0f;
            #pragma unroll
            for (int b = 0; b < 4; ++b) {
                // cA = {0.1,-1,-1,-1}; cB = {-1,0.1,-1,-1}
                float cb = (!isB ? (b == 0) : (b == 1)) ? 0.1f : -1.0f;
                int off = 9 * b;       // {0,9,18,27}
                int cor = 9 * b + 8;   // {8,17,26,35}
                float uim = (m == off + i ? 1.0f : 0.0f) + (m == cor ? hiv[b] : 0.0f);
                float ujn = (n == off + j ? 1.0f : 0.0f) + (n == cor ? hjv[b] : 0.0f);
                float ujm = (m == off + j ? 1.0f : 0.0f) + (m == cor ? hjv[b] : 0.0f);
                float uin = (n == off + i ? 1.0f : 0.0f) + (n == cor ? hiv[b] : 0.0f);
                aij += cb * uim * ujn;
                aji += cb * ujm * uin;
            }
            // b = 4 term: coefficient +1, pure delta at base 36 (A) / 44 (B)
            int base4 = isB ? 44 : 36;
            if (m == base4 + i && n == base4 + j) aij += 1.0f;
            if (m == base4 + j && n == base4 + i) aji += 1.0f;
            // diag_term: I8[i,j] * D6869[m,n]
            if (i == j && ((m == 68 && n == 69) || (m == 69 && n == 68))) {
                aij += 1.0f;
                aji += 1.0f;
            }
            float s = (i == j) ? 0.5f : 1.0f;
            val = (aij + aji) * s;
        } else {
            // ---- A2[k2] sparse matrices ----
            int k2 = k - 72;
            float v = 0.0f;
            if (k2 < 4) {
                int lo = 9 * k2;  // {0,9,18,27}
                if (m == n) {
                    if (m >= lo && m < lo + 8)      v = 400.0f;
                    else if (m == lo + 8)           v = -1.0f;
                    else if (m == 52 + k2)          v = 1.0f;
                }
            } else if (k2 < 8) {
                int q = k2 - 4;            // 0..3
                int cpos = 9 * q + 8;      // {8,17,26,35}
                float csgn = (q < 2) ? -1.0f : 1.0f;
                if (m == n) {
                    if (m == cpos)          v = csgn;
                    else if (m == 56 + q)   v = 1.0f;
                } else {
                    int base = 60 + 2 * q;
                    if ((m == base && n == base + 1) || (m == base + 1 && n == base))
                        v = 1.0f;
                }
            } else if (k2 < 12) {
                int p = 60 + 2 * (k2 - 8);  // {60,62,64,66}
                if (m == p && n == p) v = 1.0f;
            } else {  // k2 == 12
                if (m == 68 && n == 68) v = 1.0f;
            }
            val = v;
        }
        out[idx] = -val;
    } else if (idx < A0_OFF) {
        // ---- second output: -b, 85 elements ----
        int p = idx - B_OFF;
        float bv = 0.0f;
        bool one = (p == 0 || p == 8 || p == 15 || p == 21 ||
                    p == 26 || p == 30 || p == 33 || p == 35 ||
                    p == 36 || p == 44 || p == 51 || p == 57 ||
                    p == 62 || p == 66 || p == 69 || p == 71);
        if (one)                      bv = 1.0f;
        else if (p >= 76 && p < 80)   bv = v1[p - 76];
        else if (p >= 80)             bv = 0.5f * c[0];
        out[idx] = -bv;
    } else {
        // ---- third output: A0, 70x70 (NOT negated) ----
        int r = idx - A0_OFF;
        int m = r / MDIM;
        int n = r - m * MDIM;
        float v = 0.0f;
        if (m == n) {
            if (m == 8 || m == 17)                                   v = -0.0004f;
            else if (m == 61 || m == 63 || m == 65 || m == 67 || m == 69) v = 1.0f;
        } else {
            int lo = m < n ? m : n;
            int hi = m < n ? n : m;
            if (hi == lo + 1 && lo >= 60 && lo <= 66 && ((lo & 1) == 0)) {
                int q = (lo - 60) >> 1;     // 0..3
                v = t[q ^ 2];               // perm {2,3,0,1}
            }
        }
        out[idx] = v;
    }
}

extern "C" void kernel_launch(void* const* d_in, const int* in_sizes, int n_in,
                              void* d_out, int out_size, void* d_ws, size_t ws_size,
                              hipStream_t stream) {
    // setup_inputs order: rho1(0), mu1(1), v1(2), t(3), H1(4), c(5)
    const float* v1 = (const float*)d_in[2];
    const float* t  = (const float*)d_in[3];
    const float* H1 = (const float*)d_in[4];
    const float* c  = (const float*)d_in[5];
    float* out = (float*)d_out;

    const int threads = 256;
    const int blocks = (TOT + threads - 1) / threads;  // 1647
    z1_fill_kernel<<<blocks, threads, 0, stream>>>(v1, t, H1, c, out);
}